// Round 13
// baseline (431.145 us; speedup 1.0000x reference)
//
#include <hip/hip_runtime.h>
#include <math.h>

typedef _Float16 f16;
typedef _Float16 f16x8 __attribute__((ext_vector_type(8)));
typedef float    f32x4 __attribute__((ext_vector_type(4)));
typedef unsigned int u32;
typedef unsigned long long u64;

#define NHEADS 128
#define KLEN   8192
#define DDIM   128
#define SDIM   256
#define NROWS  (NHEADS * KLEN)       // 1,048,576 k-rows
#define SCALE  1.2533141373155003f   // sqrt(pi/2)
#define TAU    2e-5f                 // suspect threshold (validated rounds 3/7/9)

// ---- workspace layout ----
// [0, 1MiB)            : qs16 f16 [128 heads][16 q][256 s]
// [1MiB, +64KiB)       : Gfh  f16 fragment-ordered hi   [tl16][c4][lane64][8]
// [+64K, +128K)        : Gfl  f16 fragment-ordered lo*4096
// [+128K, +256K)       : Gt   f32 [256 s][128 d]  (exact, transposed; fixup)
// [2MiB, 2MiB+32MiB)   : packed sign bits, u32[1M rows][8]
// suspect MASK (u32[1M rows][8], 32MB) lives in d_out (dead until est).
#define QS_OFF     0
#define GFH_OFF    (1u << 20)
#define GFL_OFF    ((1u << 20) + (64u << 10))
#define GT_OFF     ((1u << 20) + (128u << 10))
#define PACKED_OFF (2u << 20)

// ------------------------------------------------------------------
// Sequential f32 dot, d-ascending, single-rounding FMA per step —
// bitwise-matches the numpy reference path (validated round 3).
__device__ __forceinline__ float seq_dot_np(const float* __restrict__ a,
                                            const float* __restrict__ gcol) {
  float acc = 0.0f;
  #pragma unroll 8
  for (int d = 0; d < DDIM; ++d)
    acc = __builtin_fmaf(a[d], gcol[d], acc);
  return acc;
}

// ------------------------------------------------------------------
// prep: q_sketch = q @ G  (f32 accumulate, store f16)
__global__ void prep_qs_kernel(const float* __restrict__ q,
                               const float* __restrict__ G,
                               f16* __restrict__ qs16) {
  int idx = blockIdx.x * 256 + threadIdx.x;      // 524288
  int s  = idx & 255;
  int hq = idx >> 8;
  const float* qr = q + (size_t)hq * DDIM;
  float acc = 0.f;
  #pragma unroll 8
  for (int d = 0; d < DDIM; ++d) acc += qr[d] * G[d * SDIM + s];
  qs16[idx] = (f16)acc;
}

// prep: G -> MFMA-fragment-ordered f16 hi/lo (B-load = lane-contiguous)
// + f32 transposed exact copy for fixup.
// Fragment: B[kk][n] for tile tl, quarter c: n = lane&15 -> s = tl*16+n,
// kk = 8*(lane>>4)+j -> d = c*32 + (lane>>4)*8 + j.
__global__ void prep_g_kernel(const float* __restrict__ G,
                              f16* __restrict__ gfh, f16* __restrict__ gfl,
                              float* __restrict__ gt) {
  int t = blockIdx.x * 256 + threadIdx.x;        // 4096 threads
  int tl   = t >> 8;
  int c    = (t >> 6) & 3;
  int lane = t & 63;
  int s  = tl * 16 + (lane & 15);
  int d0 = c * 32 + (lane >> 4) * 8;
  f16x8 hh, ll;
  #pragma unroll
  for (int j = 0; j < 8; ++j) {
    float g = G[(size_t)(d0 + j) * SDIM + s];
    f16 h = (f16)g;
    hh[j] = h;
    ll[j] = (f16)((g - (float)h) * 4096.0f);
    gt[(size_t)s * DDIM + d0 + j] = g;
  }
  *(f16x8*)(gfh + (size_t)t * 8) = hh;
  *(f16x8*)(gfl + (size_t)t * 8) = ll;
}

// ------------------------------------------------------------------
// Pass A: proj = k @ G via f16x3 MFMA emulation (validated arithmetic).
// 16 rows/wave (R7 register shape: ~52 VGPR + ~32 AGPR -> ~6 waves/SIMD)
// + R12's fragment-ordered coalesced B (1KB/instr from L2; the fix for
// R7's 16-way scatter). No LDS, no barriers. The block's 4 waves read
// identical B addresses in the same order -> L1 temporal reuse.
// grid: 16384 blocks * 256 thr; wave w owns rows blockIdx*64 + w*16.
__launch_bounds__(256)
__global__ void proj_sign_kernel(const float* __restrict__ kmat,
                                 const f16* __restrict__ gfh,
                                 const f16* __restrict__ gfl,
                                 u32* __restrict__ packed,
                                 u32* __restrict__ smask) {
  const int tid  = threadIdx.x;
  const int lane = tid & 63;
  const int w    = tid >> 6;                     // wave 0..3
  const int g4 = lane >> 4;
  const int ln = lane & 15;

  const int base = blockIdx.x * 64 + w * 16;     // this wave's 16 rows

  // ---- A fragments (hi/lo f16 split) for 16 rows ----
  // A[m][kk]: m = lane&15, kk = 8*(lane>>4)+j
  f16x8 Ah[4], Al[4];
  {
    const float* kr = kmat + (size_t)(base + ln) * DDIM;
    #pragma unroll
    for (int c = 0; c < 4; ++c) {
      const float* p0 = kr + c * 32 + g4 * 8;
      float4 a0 = *(const float4*)p0;
      float4 a1 = *(const float4*)(p0 + 4);
      float af[8] = {a0.x, a0.y, a0.z, a0.w, a1.x, a1.y, a1.z, a1.w};
      f16x8 hh, ll;
      #pragma unroll
      for (int j = 0; j < 8; ++j) {
        f16 h = (f16)af[j];
        hh[j] = h;
        ll[j] = (f16)((af[j] - (float)h) * 4096.0f);
      }
      Ah[c] = hh;
      Al[c] = ll;
    }
  }

  u32 pw[8] = {0};   // packed sign words  (lane<16: row base+lane)
  u32 sw[8] = {0};   // suspect mask words

  const size_t loff = (size_t)lane * 8;          // lane-contiguous frag base

  #pragma unroll
  for (int tl = 0; tl < 16; ++tl) {              // 16 s-tiles of 16
    // B frags: coalesced 16B/lane from fragment-ordered G
    f16x8 Bh[4], Bl[4];
    #pragma unroll
    for (int c = 0; c < 4; ++c) {
      size_t o = (size_t)(tl * 4 + c) * 512 + loff;
      Bh[c] = *(const f16x8*)(gfh + o);
      Bl[c] = *(const f16x8*)(gfl + o);
    }
    // f16x3 emulation, 3 INDEPENDENT 4-MFMA chains (ILP). Summation
    // order differs from np; fine since emul err ~1e-6 << TAU.
    f32x4 ah = {0,0,0,0}, aa = {0,0,0,0}, ab = {0,0,0,0};
    #pragma unroll
    for (int c = 0; c < 4; ++c) {
      ah = __builtin_amdgcn_mfma_f32_16x16x32_f16(Ah[c], Bh[c], ah, 0, 0, 0);
      aa = __builtin_amdgcn_mfma_f32_16x16x32_f16(Ah[c], Bl[c], aa, 0, 0, 0);
      ab = __builtin_amdgcn_mfma_f32_16x16x32_f16(Al[c], Bh[c], ab, 0, 0, 0);
    }
    float p[4];
    #pragma unroll
    for (int r = 0; r < 4; ++r)
      p[r] = ah[r] + (aa[r] + ab[r]) * 2.44140625e-4f;   // 1/4096

    // ---- sign ballots ----
    {
      u64 b0 = __ballot(p[0] > 0.0f ? 1 : 0);
      u64 b1 = __ballot(p[1] > 0.0f ? 1 : 0);
      u64 b2 = __ballot(p[2] > 0.0f ? 1 : 0);
      u64 b3 = __ballot(p[3] > 0.0f ? 1 : 0);
      if (lane < 16) {
        int r = lane & 3;
        u64 b = (r == 0) ? b0 : (r == 1) ? b1 : (r == 2) ? b2 : b3;
        u32 sh = 16u * (u32)(lane >> 2);
        pw[tl >> 1] |= ((u32)((b >> sh) & 0xffffu)) << (16 * (tl & 1));
      }
    }

    // ---- suspect ballots, guarded (trip prob ~0.6% per tile at 2e-5) ----
    float mn = fminf(fminf(__builtin_fabsf(p[0]), __builtin_fabsf(p[1])),
                     fminf(__builtin_fabsf(p[2]), __builtin_fabsf(p[3])));
    if (__any(mn < TAU ? 1 : 0)) {
      u64 t0 = __ballot(__builtin_fabsf(p[0]) < TAU ? 1 : 0);
      u64 t1 = __ballot(__builtin_fabsf(p[1]) < TAU ? 1 : 0);
      u64 t2 = __ballot(__builtin_fabsf(p[2]) < TAU ? 1 : 0);
      u64 t3 = __ballot(__builtin_fabsf(p[3]) < TAU ? 1 : 0);
      if (lane < 16) {
        int r = lane & 3;
        u64 t = (r == 0) ? t0 : (r == 1) ? t1 : (r == 2) ? t2 : t3;
        u32 sh = 16u * (u32)(lane >> 2);
        sw[tl >> 1] |= ((u32)((t >> sh) & 0xffffu)) << (16 * (tl & 1));
      }
    }
  }

  if (lane < 16) {
    size_t row = (size_t)(base + lane);
    uint4 v0, v1, m0, m1;
    v0.x = pw[0]; v0.y = pw[1]; v0.z = pw[2]; v0.w = pw[3];
    v1.x = pw[4]; v1.y = pw[5]; v1.z = pw[6]; v1.w = pw[7];
    m0.x = sw[0]; m0.y = sw[1]; m0.z = sw[2]; m0.w = sw[3];
    m1.x = sw[4]; m1.y = sw[5]; m1.z = sw[6]; m1.w = sw[7];
    *(uint4*)(packed + row * 8)     = v0;
    *(uint4*)(packed + row * 8 + 4) = v1;
    *(uint4*)(smask  + row * 8)     = m0;
    *(uint4*)(smask  + row * 8 + 4) = m1;
  }
}

// ------------------------------------------------------------------
// Pass B: one thread per k-row; ~6K suspects total -> mask-scan bound.
__global__ void fixup_kernel(const float* __restrict__ kmat,
                             const float* __restrict__ gt,
                             u32* __restrict__ packed,
                             const u32* __restrict__ smask) {
  int row = blockIdx.x * 256 + threadIdx.x;
  if (row >= NROWS) return;
  const u32* mp = smask + (size_t)row * 8;
  uint4 m0 = *(const uint4*)mp;
  uint4 m1 = *(const uint4*)(mp + 4);
  u32 mw[8] = {m0.x, m0.y, m0.z, m0.w, m1.x, m1.y, m1.z, m1.w};
  if (!(mw[0] | mw[1] | mw[2] | mw[3] | mw[4] | mw[5] | mw[6] | mw[7])) return;
  const float* a = kmat + (size_t)row * DDIM;
  #pragma unroll
  for (int wd = 0; wd < 8; ++wd) {
    u32 m = mw[wd];
    if (!m) continue;
    u32 pk = packed[(size_t)row * 8 + wd];
    while (m) {
      int b = __ffs(m) - 1;  m &= m - 1;
      int s = wd * 32 + b;
      float acc = seq_dot_np(a, gt + (size_t)s * DDIM);
      if (acc > 0.0f) pk |= (1u << b);
      else            pk &= ~(1u << b);
    }
    packed[(size_t)row * 8 + wd] = pk;
  }
}

// ------------------------------------------------------------------
// est = q_sketch @ sign^T, bits -> ±1 f16 on the fly, MFMA f16, f32 out
__launch_bounds__(256)
__global__ void est_kernel(const f16* __restrict__ qs16,
                           const u32* __restrict__ packed,
                           float* __restrict__ out) {
  const int tid  = threadIdx.x;
  const int lane = tid & 63;
  const int w    = tid >> 6;
  const int wg   = blockIdx.x;
  const int head   = wg >> 5;
  const int kchunk = (wg & 31) * 256;
  const int g4 = lane >> 4, ln = lane & 15;

  f16x8 aq[8];
  const f16* qb = qs16 + (size_t)head * 16 * SDIM;
  #pragma unroll
  for (int c = 0; c < 8; ++c)
    aq[c] = *(const f16x8*)(qb + ln * SDIM + c * 32 + g4 * 8);

  const int kb = kchunk + w * 64;
  #pragma unroll
  for (int kt = 0; kt < 4; ++kt) {
    int krow = kb + kt * 16 + ln;
    const u32* bp = packed + (size_t)(head * KLEN + krow) * 8;
    uint4 q0 = *(const uint4*)bp;
    uint4 q1 = *(const uint4*)(bp + 4);
    u32 b32[8] = {q0.x, q0.y, q0.z, q0.w, q1.x, q1.y, q1.z, q1.w};
    f32x4 acc = {0, 0, 0, 0};
    #pragma unroll
    for (int c = 0; c < 8; ++c) {
      u32 byte8 = (b32[c] >> (8 * g4)) & 0xffu;
      union { u32 u[4]; f16x8 h; } sv;
      #pragma unroll
      for (int pp = 0; pp < 4; ++pp) {
        u32 v = 0x3C003C00u;
        v |= ((byte8 >> (2 * pp))     & 1u) ? 0u : 0x8000u;
        v |= ((byte8 >> (2 * pp + 1)) & 1u) ? 0u : 0x80000000u;
        sv.u[pp] = v;
      }
      acc = __builtin_amdgcn_mfma_f32_16x16x32_f16(aq[c], sv.h, acc, 0, 0, 0);
    }
    float* ob = out + (size_t)(head * 16) * KLEN + kb + kt * 16 + ln;
    #pragma unroll
    for (int r = 0; r < 4; ++r) {
      int qrow = g4 * 4 + r;
      ob[(size_t)qrow * KLEN] = acc[r] * SCALE;
    }
  }
}

// ------------------------------------------------------------------
extern "C" void kernel_launch(void* const* d_in, const int* in_sizes, int n_in,
                              void* d_out, int out_size, void* d_ws, size_t ws_size,
                              hipStream_t stream) {
  const float* q = (const float*)d_in[0];
  const float* k = (const float*)d_in[1];
  const float* G = (const float*)d_in[2];
  float* out = (float*)d_out;
  char* ws = (char*)d_ws;

  f16*   qs16   = (f16*)(ws + QS_OFF);
  f16*   gfh    = (f16*)(ws + GFH_OFF);
  f16*   gfl    = (f16*)(ws + GFL_OFF);
  float* gt     = (float*)(ws + GT_OFF);
  u32*   packed = (u32*)(ws + PACKED_OFF);

  // suspect mask in d_out (32MB << 67MB); fully rewritten by proj_sign
  // each call; est overwrites d_out afterwards (stream-ordered).
  u32* smask = (u32*)d_out;

  prep_qs_kernel<<<2048, 256, 0, stream>>>(q, G, qs16);
  prep_g_kernel<<<16, 256, 0, stream>>>(G, gfh, gfl, gt);
  proj_sign_kernel<<<16384, 256, 0, stream>>>(k, gfh, gfl, packed, smask);
  fixup_kernel<<<4096, 256, 0, stream>>>(k, gt, packed, smask);
  est_kernel<<<4096, 256, 0, stream>>>(qs16, packed, out);
}

// Round 14
// 404.943 us; speedup vs baseline: 1.0647x; 1.0647x over previous
//
#include <hip/hip_runtime.h>
#include <math.h>

typedef _Float16 f16;
typedef _Float16 f16x8 __attribute__((ext_vector_type(8)));
typedef float    f32x4 __attribute__((ext_vector_type(4)));
typedef unsigned int u32;
typedef unsigned long long u64;

#define NHEADS 128
#define KLEN   8192
#define DDIM   128
#define SDIM   256
#define NROWS  (NHEADS * KLEN)       // 1,048,576 k-rows
#define SCALE  1.2533141373155003f   // sqrt(pi/2)
#define TAU    2e-5f                 // suspect threshold (validated rounds 3/7/9)

// ---- workspace layout ----
// [0, 1MiB)            : qs16 f16 [128 heads][16 q][256 s]
// [1MiB, +64KiB)       : Gfh  f16 fragment-ordered hi   [tl16][c4][lane64][8]
// [+64K, +128K)        : Gfl  f16 fragment-ordered lo*4096
// [+128K, +256K)       : Gt   f32 [256 s][128 d]  (exact, transposed; fixup)
// [2MiB, 2MiB+32MiB)   : packed sign bits, u32[1M rows][8]
// suspect MASK (u32[1M rows][8], 32MB) lives in d_out (dead until est).
#define QS_OFF     0
#define GFH_OFF    (1u << 20)
#define GFL_OFF    ((1u << 20) + (64u << 10))
#define GT_OFF     ((1u << 20) + (128u << 10))
#define PACKED_OFF (2u << 20)

// ------------------------------------------------------------------
// Sequential f32 dot, d-ascending, single-rounding FMA per step —
// bitwise-matches the numpy reference path (validated round 3).
__device__ __forceinline__ float seq_dot_np(const float* __restrict__ a,
                                            const float* __restrict__ gcol) {
  float acc = 0.0f;
  #pragma unroll 8
  for (int d = 0; d < DDIM; ++d)
    acc = __builtin_fmaf(a[d], gcol[d], acc);
  return acc;
}

// ------------------------------------------------------------------
// prep: q_sketch = q @ G  (f32 accumulate, store f16)
__global__ void prep_qs_kernel(const float* __restrict__ q,
                               const float* __restrict__ G,
                               f16* __restrict__ qs16) {
  int idx = blockIdx.x * 256 + threadIdx.x;      // 524288
  int s  = idx & 255;
  int hq = idx >> 8;
  const float* qr = q + (size_t)hq * DDIM;
  float acc = 0.f;
  #pragma unroll 8
  for (int d = 0; d < DDIM; ++d) acc += qr[d] * G[d * SDIM + s];
  qs16[idx] = (f16)acc;
}

// prep: G -> MFMA-fragment-ordered f16 hi/lo (B-load = lane-contiguous)
// + f32 transposed exact copy for fixup.
// Fragment: B[kk][n] for tile tl, quarter c: n = lane&15 -> s = tl*16+n,
// kk = 8*(lane>>4)+j -> d = c*32 + (lane>>4)*8 + j.
__global__ void prep_g_kernel(const float* __restrict__ G,
                              f16* __restrict__ gfh, f16* __restrict__ gfl,
                              float* __restrict__ gt) {
  int t = blockIdx.x * 256 + threadIdx.x;        // 4096 threads
  int tl   = t >> 8;
  int c    = (t >> 6) & 3;
  int lane = t & 63;
  int s  = tl * 16 + (lane & 15);
  int d0 = c * 32 + (lane >> 4) * 8;
  f16x8 hh, ll;
  #pragma unroll
  for (int j = 0; j < 8; ++j) {
    float g = G[(size_t)(d0 + j) * SDIM + s];
    f16 h = (f16)g;
    hh[j] = h;
    ll[j] = (f16)((g - (float)h) * 4096.0f);
    gt[(size_t)s * DDIM + d0 + j] = g;
  }
  *(f16x8*)(gfh + (size_t)t * 8) = hh;
  *(f16x8*)(gfl + (size_t)t * 8) = ll;
}

// ------------------------------------------------------------------
// Pass A: proj = k @ G via f16x3 MFMA emulation (validated arithmetic).
// R12 structure: no LDS, no barriers, fragment-ordered coalesced B from
// L2-resident G (128KB), 32 rows/wave, 256-thr blocks, grid 8192.
// NEW (R14): co-resident blocks are PHASE-STAGGERED — each block starts
// its s-tile sweep at a different rotation ((blockIdx&3)*4), so waves
// from different blocks on the same SIMD are in different phases
// (load vs MFMA vs ballot) and the pipes overlap instead of taking
// turns. Ballot/OR packing is order-independent -> bit-identical.
__launch_bounds__(256)
__global__ void proj_sign_kernel(const float* __restrict__ kmat,
                                 const f16* __restrict__ gfh,
                                 const f16* __restrict__ gfl,
                                 u32* __restrict__ packed,
                                 u32* __restrict__ smask) {
  const int tid  = threadIdx.x;
  const int lane = tid & 63;
  const int w    = tid >> 6;                     // wave 0..3
  const int g4 = lane >> 4;
  const int ln = lane & 15;

  const int base = blockIdx.x * 128 + w * 32;    // this wave's 32 rows
  const int rot  = (blockIdx.x & 3) * 4;         // phase stagger

  // ---- A fragments (hi/lo f16 split) for 32 rows (2 blocks of 16) ----
  // A[m][kk]: m = lane&15, kk = 8*(lane>>4)+j
  f16x8 Ah[2][4], Al[2][4];
  #pragma unroll
  for (int rb = 0; rb < 2; ++rb) {
    const float* kr = kmat + (size_t)(base + rb * 16 + ln) * DDIM;
    #pragma unroll
    for (int c = 0; c < 4; ++c) {
      const float* p0 = kr + c * 32 + g4 * 8;
      float4 a0 = *(const float4*)p0;
      float4 a1 = *(const float4*)(p0 + 4);
      float af[8] = {a0.x, a0.y, a0.z, a0.w, a1.x, a1.y, a1.z, a1.w};
      f16x8 hh, ll;
      #pragma unroll
      for (int j = 0; j < 8; ++j) {
        f16 h = (f16)af[j];
        hh[j] = h;
        ll[j] = (f16)((af[j] - (float)h) * 4096.0f);
      }
      Ah[rb][c] = hh;
      Al[rb][c] = ll;
    }
  }

  u32 pw[2][8] = {{0}};   // packed sign words  (lane<16: row rb*16+lane)
  u32 sw[2][8] = {{0}};   // suspect mask words

  const size_t loff = (size_t)lane * 8;          // lane-contiguous frag base

  #pragma unroll
  for (int t = 0; t < 16; ++t) {                 // 16 s-tiles of 16
    const int tl = (rot + t) & 15;               // phase-staggered order
    // B frags: coalesced 16B/lane from fragment-ordered G
    f16x8 Bh[4], Bl[4];
    #pragma unroll
    for (int c = 0; c < 4; ++c) {
      size_t o = (size_t)(tl * 4 + c) * 512 + loff;
      Bh[c] = *(const f16x8*)(gfh + o);
      Bl[c] = *(const f16x8*)(gfl + o);
    }
    // f16x3 emulation, 6 INDEPENDENT 4-MFMA chains (ILP). Summation
    // order differs from np; fine since emul err ~1e-6 << TAU.
    f32x4 ah0 = {0,0,0,0}, aa0 = {0,0,0,0}, ab0 = {0,0,0,0};
    f32x4 ah1 = {0,0,0,0}, aa1 = {0,0,0,0}, ab1 = {0,0,0,0};
    #pragma unroll
    for (int c = 0; c < 4; ++c) {
      ah0 = __builtin_amdgcn_mfma_f32_16x16x32_f16(Ah[0][c], Bh[c], ah0, 0, 0, 0);
      aa0 = __builtin_amdgcn_mfma_f32_16x16x32_f16(Ah[0][c], Bl[c], aa0, 0, 0, 0);
      ab0 = __builtin_amdgcn_mfma_f32_16x16x32_f16(Al[0][c], Bh[c], ab0, 0, 0, 0);
      ah1 = __builtin_amdgcn_mfma_f32_16x16x32_f16(Ah[1][c], Bh[c], ah1, 0, 0, 0);
      aa1 = __builtin_amdgcn_mfma_f32_16x16x32_f16(Ah[1][c], Bl[c], aa1, 0, 0, 0);
      ab1 = __builtin_amdgcn_mfma_f32_16x16x32_f16(Al[1][c], Bh[c], ab1, 0, 0, 0);
    }
    float p[2][4];
    #pragma unroll
    for (int r = 0; r < 4; ++r) {
      p[0][r] = ah0[r] + (aa0[r] + ab0[r]) * 2.44140625e-4f;   // 1/4096
      p[1][r] = ah1[r] + (aa1[r] + ab1[r]) * 2.44140625e-4f;
    }

    // ---- sign ballots ----
    #pragma unroll
    for (int rb = 0; rb < 2; ++rb) {
      u64 b0 = __ballot(p[rb][0] > 0.0f ? 1 : 0);
      u64 b1 = __ballot(p[rb][1] > 0.0f ? 1 : 0);
      u64 b2 = __ballot(p[rb][2] > 0.0f ? 1 : 0);
      u64 b3 = __ballot(p[rb][3] > 0.0f ? 1 : 0);
      if (lane < 16) {
        int r = lane & 3;
        u64 b = (r == 0) ? b0 : (r == 1) ? b1 : (r == 2) ? b2 : b3;
        u32 sh = 16u * (u32)(lane >> 2);
        pw[rb][tl >> 1] |= ((u32)((b >> sh) & 0xffffu)) << (16 * (tl & 1));
      }
    }

    // ---- suspect ballots, guarded (trip prob ~1% per tile at 2e-5) ----
    float mn = __builtin_fabsf(p[0][0]);
    #pragma unroll
    for (int rb = 0; rb < 2; ++rb)
      #pragma unroll
      for (int r = 0; r < 4; ++r)
        mn = fminf(mn, __builtin_fabsf(p[rb][r]));
    if (__any(mn < TAU ? 1 : 0)) {
      #pragma unroll
      for (int rb = 0; rb < 2; ++rb) {
        u64 t0 = __ballot(__builtin_fabsf(p[rb][0]) < TAU ? 1 : 0);
        u64 t1 = __ballot(__builtin_fabsf(p[rb][1]) < TAU ? 1 : 0);
        u64 t2 = __ballot(__builtin_fabsf(p[rb][2]) < TAU ? 1 : 0);
        u64 t3 = __ballot(__builtin_fabsf(p[rb][3]) < TAU ? 1 : 0);
        if (lane < 16) {
          int r = lane & 3;
          u64 tt = (r == 0) ? t0 : (r == 1) ? t1 : (r == 2) ? t2 : t3;
          u32 sh = 16u * (u32)(lane >> 2);
          sw[rb][tl >> 1] |= ((u32)((tt >> sh) & 0xffffu)) << (16 * (tl & 1));
        }
      }
    }
  }

  if (lane < 16) {
    #pragma unroll
    for (int rb = 0; rb < 2; ++rb) {
      size_t row = (size_t)(base + rb * 16 + lane);
      uint4 v0, v1, m0, m1;
      v0.x = pw[rb][0]; v0.y = pw[rb][1]; v0.z = pw[rb][2]; v0.w = pw[rb][3];
      v1.x = pw[rb][4]; v1.y = pw[rb][5]; v1.z = pw[rb][6]; v1.w = pw[rb][7];
      m0.x = sw[rb][0]; m0.y = sw[rb][1]; m0.z = sw[rb][2]; m0.w = sw[rb][3];
      m1.x = sw[rb][4]; m1.y = sw[rb][5]; m1.z = sw[rb][6]; m1.w = sw[rb][7];
      *(uint4*)(packed + row * 8)     = v0;
      *(uint4*)(packed + row * 8 + 4) = v1;
      *(uint4*)(smask  + row * 8)     = m0;
      *(uint4*)(smask  + row * 8 + 4) = m1;
    }
  }
}

// ------------------------------------------------------------------
// Pass B: one thread per k-row; ~6K suspects total -> mask-scan bound.
__global__ void fixup_kernel(const float* __restrict__ kmat,
                             const float* __restrict__ gt,
                             u32* __restrict__ packed,
                             const u32* __restrict__ smask) {
  int row = blockIdx.x * 256 + threadIdx.x;
  if (row >= NROWS) return;
  const u32* mp = smask + (size_t)row * 8;
  uint4 m0 = *(const uint4*)mp;
  uint4 m1 = *(const uint4*)(mp + 4);
  u32 mw[8] = {m0.x, m0.y, m0.z, m0.w, m1.x, m1.y, m1.z, m1.w};
  if (!(mw[0] | mw[1] | mw[2] | mw[3] | mw[4] | mw[5] | mw[6] | mw[7])) return;
  const float* a = kmat + (size_t)row * DDIM;
  #pragma unroll
  for (int wd = 0; wd < 8; ++wd) {
    u32 m = mw[wd];
    if (!m) continue;
    u32 pk = packed[(size_t)row * 8 + wd];
    while (m) {
      int b = __ffs(m) - 1;  m &= m - 1;
      int s = wd * 32 + b;
      float acc = seq_dot_np(a, gt + (size_t)s * DDIM);
      if (acc > 0.0f) pk |= (1u << b);
      else            pk &= ~(1u << b);
    }
    packed[(size_t)row * 8 + wd] = pk;
  }
}

// ------------------------------------------------------------------
// est = q_sketch @ sign^T, bits -> ±1 f16 on the fly, MFMA f16, f32 out
__launch_bounds__(256)
__global__ void est_kernel(const f16* __restrict__ qs16,
                           const u32* __restrict__ packed,
                           float* __restrict__ out) {
  const int tid  = threadIdx.x;
  const int lane = tid & 63;
  const int w    = tid >> 6;
  const int wg   = blockIdx.x;
  const int head   = wg >> 5;
  const int kchunk = (wg & 31) * 256;
  const int g4 = lane >> 4, ln = lane & 15;

  f16x8 aq[8];
  const f16* qb = qs16 + (size_t)head * 16 * SDIM;
  #pragma unroll
  for (int c = 0; c < 8; ++c)
    aq[c] = *(const f16x8*)(qb + ln * SDIM + c * 32 + g4 * 8);

  const int kb = kchunk + w * 64;
  #pragma unroll
  for (int kt = 0; kt < 4; ++kt) {
    int krow = kb + kt * 16 + ln;
    const u32* bp = packed + (size_t)(head * KLEN + krow) * 8;
    uint4 q0 = *(const uint4*)bp;
    uint4 q1 = *(const uint4*)(bp + 4);
    u32 b32[8] = {q0.x, q0.y, q0.z, q0.w, q1.x, q1.y, q1.z, q1.w};
    f32x4 acc = {0, 0, 0, 0};
    #pragma unroll
    for (int c = 0; c < 8; ++c) {
      u32 byte8 = (b32[c] >> (8 * g4)) & 0xffu;
      union { u32 u[4]; f16x8 h; } sv;
      #pragma unroll
      for (int pp = 0; pp < 4; ++pp) {
        u32 v = 0x3C003C00u;
        v |= ((byte8 >> (2 * pp))     & 1u) ? 0u : 0x8000u;
        v |= ((byte8 >> (2 * pp + 1)) & 1u) ? 0u : 0x80000000u;
        sv.u[pp] = v;
      }
      acc = __builtin_amdgcn_mfma_f32_16x16x32_f16(aq[c], sv.h, acc, 0, 0, 0);
    }
    float* ob = out + (size_t)(head * 16) * KLEN + kb + kt * 16 + ln;
    #pragma unroll
    for (int r = 0; r < 4; ++r) {
      int qrow = g4 * 4 + r;
      ob[(size_t)qrow * KLEN] = acc[r] * SCALE;
    }
  }
}

// ------------------------------------------------------------------
extern "C" void kernel_launch(void* const* d_in, const int* in_sizes, int n_in,
                              void* d_out, int out_size, void* d_ws, size_t ws_size,
                              hipStream_t stream) {
  const float* q = (const float*)d_in[0];
  const float* k = (const float*)d_in[1];
  const float* G = (const float*)d_in[2];
  float* out = (float*)d_out;
  char* ws = (char*)d_ws;

  f16*   qs16   = (f16*)(ws + QS_OFF);
  f16*   gfh    = (f16*)(ws + GFH_OFF);
  f16*   gfl    = (f16*)(ws + GFL_OFF);
  float* gt     = (float*)(ws + GT_OFF);
  u32*   packed = (u32*)(ws + PACKED_OFF);

  // suspect mask in d_out (32MB << 67MB); fully rewritten by proj_sign
  // each call; est overwrites d_out afterwards (stream-ordered).
  u32* smask = (u32*)d_out;

  prep_qs_kernel<<<2048, 256, 0, stream>>>(q, G, qs16);
  prep_g_kernel<<<16, 256, 0, stream>>>(G, gfh, gfl, gt);
  proj_sign_kernel<<<8192, 256, 0, stream>>>(k, gfh, gfl, packed, smask);
  fixup_kernel<<<4096, 256, 0, stream>>>(k, gt, packed, smask);
  est_kernel<<<4096, 256, 0, stream>>>(qs16, packed, out);
}

// Round 15
// 307.438 us; speedup vs baseline: 1.4024x; 1.3172x over previous
//
#include <hip/hip_runtime.h>
#include <math.h>

typedef _Float16 f16;
typedef _Float16 f16x4 __attribute__((ext_vector_type(4)));
typedef _Float16 f16x8 __attribute__((ext_vector_type(8)));
typedef float    f32x4 __attribute__((ext_vector_type(4)));
typedef unsigned int u32;
typedef unsigned long long u64;

#define NHEADS 128
#define KLEN   8192
#define DDIM   128
#define SDIM   256
#define NROWS  (NHEADS * KLEN)       // 1,048,576 k-rows
#define SCALE  1.2533141373155003f   // sqrt(pi/2)
#define TAU    2e-5f                 // suspect threshold (validated rounds 3/7/9)

// ---- workspace layout ----
// [0, 1MiB)            : qs16 f16 [128 heads][16 q][256 s]
// [1MiB, +64KiB)       : Gfh  f16 fragment-ordered hi   [tl16][kc4][lane64][8]
// [+64K, +128K)        : Gfl  f16 fragment-ordered lo*4096
// [+128K, +256K)       : Gt   f32 [256 s][128 d]  (exact, transposed; fixup)
// [2MiB, 2MiB+32MiB)   : packed sign bits, u32[1M rows][8]
// suspect MASK (u32[1M rows][8], 32MB) lives in d_out (dead until est).
#define QS_OFF     0
#define GFH_OFF    (1u << 20)
#define GFL_OFF    ((1u << 20) + (64u << 10))
#define GT_OFF     ((1u << 20) + (128u << 10))
#define PACKED_OFF (2u << 20)

// ------------------------------------------------------------------
// Sequential f32 dot, d-ascending, single-rounding FMA per step —
// bitwise-matches the numpy reference path (validated round 3).
__device__ __forceinline__ float seq_dot_np(const float* __restrict__ a,
                                            const float* __restrict__ gcol) {
  float acc = 0.0f;
  #pragma unroll 8
  for (int d = 0; d < DDIM; ++d)
    acc = __builtin_fmaf(a[d], gcol[d], acc);
  return acc;
}

// ------------------------------------------------------------------
// prep: q_sketch = q @ G  (f32 accumulate, store f16)
__global__ void prep_qs_kernel(const float* __restrict__ q,
                               const float* __restrict__ G,
                               f16* __restrict__ qs16) {
  int idx = blockIdx.x * 256 + threadIdx.x;      // 524288
  int s  = idx & 255;
  int hq = idx >> 8;
  const float* qr = q + (size_t)hq * DDIM;
  float acc = 0.f;
  #pragma unroll 8
  for (int d = 0; d < DDIM; ++d) acc += qr[d] * G[d * SDIM + s];
  qs16[idx] = (f16)acc;
}

// prep: G -> MFMA-fragment-ordered f16 hi/lo + f32 transposed exact copy.
// Fragment (A or B, same formula): idx lane&15 -> s = tl*16+(lane&15),
// kk = 8*(lane>>4)+j -> d = kc*32 + (lane>>4)*8 + j.
__global__ void prep_g_kernel(const float* __restrict__ G,
                              f16* __restrict__ gfh, f16* __restrict__ gfl,
                              float* __restrict__ gt) {
  int t = blockIdx.x * 256 + threadIdx.x;        // 4096 threads
  int tl   = t >> 8;
  int c    = (t >> 6) & 3;
  int lane = t & 63;
  int s  = tl * 16 + (lane & 15);
  int d0 = c * 32 + (lane >> 4) * 8;
  f16x8 hh, ll;
  #pragma unroll
  for (int j = 0; j < 8; ++j) {
    float g = G[(size_t)(d0 + j) * SDIM + s];
    f16 h = (f16)g;
    hh[j] = h;
    ll[j] = (f16)((g - (float)h) * 4096.0f);
    gt[(size_t)s * DDIM + d0 + j] = g;
  }
  *(f16x8*)(gfh + (size_t)t * 8) = hh;
  *(f16x8*)(gfl + (size_t)t * 8) = ll;
}

// ------------------------------------------------------------------
// Pass A (G-STATIONARY): each wave holds G-fragments for its 32-s strip
// in registers (64 VGPR, loaded once); k streams through LDS. Block =
// 512 thr = 8 waves = 8 strips = full 256 s; block owns 256 rows = 16
// k-tiles of 16. Per tile: block stages 8KB k f32 -> hi/lo f16 frags in
// LDS (converted ONCE), all 8 waves consume; 24 MFMA/wave/tile.
// D = (s x row): lane builds its 8 bits locally, OR across the 4-lane
// column group via shfl_xor, lanes 0-15 store u32 per row per strip.
// f16x3 arithmetic identical to validated R12 (3 chains over kc).
__launch_bounds__(512, 1)
__global__ void proj_sign_kernel(const float* __restrict__ kmat,
                                 const f16* __restrict__ gfh,
                                 const f16* __restrict__ gfl,
                                 u32* __restrict__ packed,
                                 u32* __restrict__ smask) {
  __shared__ __align__(16) f16 lds[2][4][64][8];   // [hilo][kc][lane][8] = 8KB

  const int tid  = threadIdx.x;
  const int lane = tid & 63;
  const int w    = tid >> 6;                     // wave 0..7 = s-strip
  const int g4 = lane >> 4;
  const int ln = lane & 15;
  const size_t rowbase = (size_t)blockIdx.x * 256;

  // ---- G fragments (stationary A-operand) for strip [w*32, w*32+32) ----
  f16x8 Gh[2][4], Gl[2][4];
  #pragma unroll
  for (int mt = 0; mt < 2; ++mt)
    #pragma unroll
    for (int kc = 0; kc < 4; ++kc) {
      size_t o = ((size_t)((w * 2 + mt) * 4 + kc) * 64 + lane) * 8;
      Gh[mt][kc] = *(const f16x8*)(gfh + o);
      Gl[mt][kc] = *(const f16x8*)(gfl + o);
    }

  // ---- staging indices: thread -> (row, d-quad) of the 16x128 k-tile ----
  const int srl = tid >> 5;                      // 0..15 local row
  const int sd0 = (tid & 31) * 4;                // d offset 0..124
  const int skc = sd0 >> 5;
  const int slf = srl | (((sd0 >> 3) & 3) << 4); // fragment lane
  const int sj0 = sd0 & 7;                       // 0 or 4

  float4 rv = *(const float4*)(kmat + (rowbase + srl) * DDIM + sd0);

  for (int t = 0; t < 16; ++t) {
    // convert this tile's quad and write to LDS fragment slots
    f16x4 h4, l4;
    {
      float vv0 = rv.x, vv1 = rv.y, vv2 = rv.z, vv3 = rv.w;
      f16 h;
      h = (f16)vv0; h4[0] = h; l4[0] = (f16)((vv0 - (float)h) * 4096.0f);
      h = (f16)vv1; h4[1] = h; l4[1] = (f16)((vv1 - (float)h) * 4096.0f);
      h = (f16)vv2; h4[2] = h; l4[2] = (f16)((vv2 - (float)h) * 4096.0f);
      h = (f16)vv3; h4[3] = h; l4[3] = (f16)((vv3 - (float)h) * 4096.0f);
    }
    // prefetch next tile early (latency hides under compute below)
    float4 rn;
    if (t < 15)
      rn = *(const float4*)(kmat + (rowbase + (size_t)(t + 1) * 16 + srl) * DDIM + sd0);
    *(f16x4*)&lds[0][skc][slf][sj0] = h4;
    *(f16x4*)&lds[1][skc][slf][sj0] = l4;
    __syncthreads();

    // ---- compute: 24 MFMA (2 m-tiles x 4 kc x 3 chains) ----
    f32x4 ah0 = {0,0,0,0}, aa0 = {0,0,0,0}, ab0 = {0,0,0,0};
    f32x4 ah1 = {0,0,0,0}, aa1 = {0,0,0,0}, ab1 = {0,0,0,0};
    #pragma unroll
    for (int kc = 0; kc < 4; ++kc) {
      f16x8 Bh = *(const f16x8*)&lds[0][kc][lane][0];
      f16x8 Bl = *(const f16x8*)&lds[1][kc][lane][0];
      ah0 = __builtin_amdgcn_mfma_f32_16x16x32_f16(Gh[0][kc], Bh, ah0, 0, 0, 0);
      aa0 = __builtin_amdgcn_mfma_f32_16x16x32_f16(Gh[0][kc], Bl, aa0, 0, 0, 0);
      ab0 = __builtin_amdgcn_mfma_f32_16x16x32_f16(Gl[0][kc], Bh, ab0, 0, 0, 0);
      ah1 = __builtin_amdgcn_mfma_f32_16x16x32_f16(Gh[1][kc], Bh, ah1, 0, 0, 0);
      aa1 = __builtin_amdgcn_mfma_f32_16x16x32_f16(Gh[1][kc], Bl, aa1, 0, 0, 0);
      ab1 = __builtin_amdgcn_mfma_f32_16x16x32_f16(Gl[1][kc], Bh, ab1, 0, 0, 0);
    }
    float p[2][4];
    #pragma unroll
    for (int r = 0; r < 4; ++r) {
      p[0][r] = ah0[r] + (aa0[r] + ab0[r]) * 2.44140625e-4f;   // 1/4096
      p[1][r] = ah1[r] + (aa1[r] + ab1[r]) * 2.44140625e-4f;
    }

    // ---- per-lane bit build: lane owns col (row ln), rows m = g4*4+r ----
    u32 pbits = 0, sbits = 0;
    #pragma unroll
    for (int mt = 0; mt < 2; ++mt)
      #pragma unroll
      for (int r = 0; r < 4; ++r)
        if (p[mt][r] > 0.0f) pbits |= (1u << (mt * 16 + g4 * 4 + r));
    float mn = __builtin_fabsf(p[0][0]);
    #pragma unroll
    for (int mt = 0; mt < 2; ++mt)
      #pragma unroll
      for (int r = 0; r < 4; ++r)
        mn = fminf(mn, __builtin_fabsf(p[mt][r]));
    if (__any(mn < TAU ? 1 : 0)) {
      #pragma unroll
      for (int mt = 0; mt < 2; ++mt)
        #pragma unroll
        for (int r = 0; r < 4; ++r)
          if (__builtin_fabsf(p[mt][r]) < TAU) sbits |= (1u << (mt * 16 + g4 * 4 + r));
    }
    // OR across the 4-lane column group {ln, ln+16, ln+32, ln+48}
    pbits |= __shfl_xor(pbits, 16);  pbits |= __shfl_xor(pbits, 32);
    sbits |= __shfl_xor(sbits, 16);  sbits |= __shfl_xor(sbits, 32);
    if (lane < 16) {
      size_t row = rowbase + (size_t)t * 16 + ln;
      packed[row * 8 + w] = pbits;
      smask [row * 8 + w] = sbits;
    }
    __syncthreads();                             // before overwriting LDS
    if (t < 15) rv = rn;
  }
}

// ------------------------------------------------------------------
// Pass B: one thread per k-row; ~6K suspects total -> mask-scan bound.
__global__ void fixup_kernel(const float* __restrict__ kmat,
                             const float* __restrict__ gt,
                             u32* __restrict__ packed,
                             const u32* __restrict__ smask) {
  int row = blockIdx.x * 256 + threadIdx.x;
  if (row >= NROWS) return;
  const u32* mp = smask + (size_t)row * 8;
  uint4 m0 = *(const uint4*)mp;
  uint4 m1 = *(const uint4*)(mp + 4);
  u32 mw[8] = {m0.x, m0.y, m0.z, m0.w, m1.x, m1.y, m1.z, m1.w};
  if (!(mw[0] | mw[1] | mw[2] | mw[3] | mw[4] | mw[5] | mw[6] | mw[7])) return;
  const float* a = kmat + (size_t)row * DDIM;
  #pragma unroll
  for (int wd = 0; wd < 8; ++wd) {
    u32 m = mw[wd];
    if (!m) continue;
    u32 pk = packed[(size_t)row * 8 + wd];
    while (m) {
      int b = __ffs(m) - 1;  m &= m - 1;
      int s = wd * 32 + b;
      float acc = seq_dot_np(a, gt + (size_t)s * DDIM);
      if (acc > 0.0f) pk |= (1u << b);
      else            pk &= ~(1u << b);
    }
    packed[(size_t)row * 8 + wd] = pk;
  }
}

// ------------------------------------------------------------------
// est = q_sketch @ sign^T, bits -> ±1 f16 on the fly, MFMA f16, f32 out
__launch_bounds__(256)
__global__ void est_kernel(const f16* __restrict__ qs16,
                           const u32* __restrict__ packed,
                           float* __restrict__ out) {
  const int tid  = threadIdx.x;
  const int lane = tid & 63;
  const int w    = tid >> 6;
  const int wg   = blockIdx.x;
  const int head   = wg >> 5;
  const int kchunk = (wg & 31) * 256;
  const int g4 = lane >> 4, ln = lane & 15;

  f16x8 aq[8];
  const f16* qb = qs16 + (size_t)head * 16 * SDIM;
  #pragma unroll
  for (int c = 0; c < 8; ++c)
    aq[c] = *(const f16x8*)(qb + ln * SDIM + c * 32 + g4 * 8);

  const int kb = kchunk + w * 64;
  #pragma unroll
  for (int kt = 0; kt < 4; ++kt) {
    int krow = kb + kt * 16 + ln;
    const u32* bp = packed + (size_t)(head * KLEN + krow) * 8;
    uint4 q0 = *(const uint4*)bp;
    uint4 q1 = *(const uint4*)(bp + 4);
    u32 b32[8] = {q0.x, q0.y, q0.z, q0.w, q1.x, q1.y, q1.z, q1.w};
    f32x4 acc = {0, 0, 0, 0};
    #pragma unroll
    for (int c = 0; c < 8; ++c) {
      u32 byte8 = (b32[c] >> (8 * g4)) & 0xffu;
      union { u32 u[4]; f16x8 h; } sv;
      #pragma unroll
      for (int pp = 0; pp < 4; ++pp) {
        u32 v = 0x3C003C00u;
        v |= ((byte8 >> (2 * pp))     & 1u) ? 0u : 0x8000u;
        v |= ((byte8 >> (2 * pp + 1)) & 1u) ? 0u : 0x80000000u;
        sv.u[pp] = v;
      }
      acc = __builtin_amdgcn_mfma_f32_16x16x32_f16(aq[c], sv.h, acc, 0, 0, 0);
    }
    float* ob = out + (size_t)(head * 16) * KLEN + kb + kt * 16 + ln;
    #pragma unroll
    for (int r = 0; r < 4; ++r) {
      int qrow = g4 * 4 + r;
      ob[(size_t)qrow * KLEN] = acc[r] * SCALE;
    }
  }
}

// ------------------------------------------------------------------
extern "C" void kernel_launch(void* const* d_in, const int* in_sizes, int n_in,
                              void* d_out, int out_size, void* d_ws, size_t ws_size,
                              hipStream_t stream) {
  const float* q = (const float*)d_in[0];
  const float* k = (const float*)d_in[1];
  const float* G = (const float*)d_in[2];
  float* out = (float*)d_out;
  char* ws = (char*)d_ws;

  f16*   qs16   = (f16*)(ws + QS_OFF);
  f16*   gfh    = (f16*)(ws + GFH_OFF);
  f16*   gfl    = (f16*)(ws + GFL_OFF);
  float* gt     = (float*)(ws + GT_OFF);
  u32*   packed = (u32*)(ws + PACKED_OFF);

  // suspect mask in d_out (32MB << 67MB); fully rewritten by proj_sign
  // each call; est overwrites d_out afterwards (stream-ordered).
  u32* smask = (u32*)d_out;

  prep_qs_kernel<<<2048, 256, 0, stream>>>(q, G, qs16);
  prep_g_kernel<<<16, 256, 0, stream>>>(G, gfh, gfl, gt);
  proj_sign_kernel<<<4096, 512, 0, stream>>>(k, gfh, gfl, packed, smask);
  fixup_kernel<<<4096, 256, 0, stream>>>(k, gt, packed, smask);
  est_kernel<<<4096, 256, 0, stream>>>(qs16, packed, out);
}